// Round 10
// baseline (356.546 us; speedup 1.0000x reference)
//
#include <hip/hip_runtime.h>

#define LAYERS 8

typedef float f32x4 __attribute__((ext_vector_type(4)));  // native vector: OK for nontemporal builtins

// One wave = one 64-row tile. 4 lanes per row (q = lane&3 picks float4 chunks
// {q, q+4, q+8, q+12}), so each global_load_dwordx4 instruction touches 16 full
// 64B lines (perfect line utilization). Reduction = 2 shfl_xor steps within the
// aligned 4-lane group. Lane ownership chosen so capture needs no cross-group
// shuffle: lane l owns row (l&3)*16 + (l>>2), captured when k == (l&3).
__global__ __launch_bounds__(256, 4)
void fraud_fused_kernel(
    const float* __restrict__ x,        // [B][64]
    const float* __restrict__ pre_w,    // [2][64]
    const float* __restrict__ pre_b,    // [2]
    const float* __restrict__ layer_w,  // [8][2][2]
    const float* __restrict__ layer_b,  // [8][2]
    const float* __restrict__ scale,    // [8][2]
    const float* __restrict__ shift,    // [8][2]
    const float* __restrict__ final_w,  // [1][2]
    const float* __restrict__ final_b,  // [1]
    const float* __restrict__ head_w,   // [1][1]
    const float* __restrict__ head_b,   // [1]
    float* __restrict__ out,            // [B]
    const int Brows)
{
    const int tid  = blockIdx.x * blockDim.x + threadIdx.x;
    const int lane = threadIdx.x & 63;
    const int q    = lane & 3;      // chunk phase within row
    const int grp  = lane >> 2;     // row sub-index within a 16-row step
    const int wave = tid >> 6;
    const int nwav = (gridDim.x * blockDim.x) >> 6;

    // per-lane pre_w fragments: chunks q, q+4, q+8, q+12 of each of the 2 rows
    const f32x4* pw4 = (const f32x4*)pre_w;
    f32x4 a0[4], a1[4];
#pragma unroll
    for (int j = 0; j < 4; ++j) {
        a0[j] = pw4[q + 4 * j];
        a1[j] = pw4[16 + q + 4 * j];
    }
    const float b0 = pre_b[0], b1 = pre_b[1];

    // fold head into final: out = h0*fw0 + h1*fw1 + fb
    const float hw  = head_w[0];
    const float fw0 = final_w[0] * hw;
    const float fw1 = final_w[1] * hw;
    const float fb  = fmaf(final_b[0], hw, head_b[0]);

    const f32x4* x4 = (const f32x4*)x;
    const int ntiles = (Brows + 63) >> 6;
    const int myrow  = (q << 4) + grp;   // owned row within the 64-row tile

    for (int tile = wave; tile < ntiles; tile += nwav) {
        const int rbase = tile << 6;
        float m0 = 0.f, m1 = 0.f;
#pragma unroll
        for (int k = 0; k < 4; ++k) {
            int row = rbase + (k << 4) + grp;
            row = min(row, Brows - 1);          // safe clamp (no-op when B%64==0)
            const f32x4* rp = x4 + (long)row * 16 + q;
            float p0 = 0.f, p1 = 0.f;
#pragma unroll
            for (int j = 0; j < 4; ++j) {
                const f32x4 v = __builtin_nontemporal_load(rp + 4 * j);
                p0 = fmaf(v.x, a0[j].x, fmaf(v.y, a0[j].y,
                     fmaf(v.z, a0[j].z, fmaf(v.w, a0[j].w, p0))));
                p1 = fmaf(v.x, a1[j].x, fmaf(v.y, a1[j].y,
                     fmaf(v.z, a1[j].z, fmaf(v.w, a1[j].w, p1))));
            }
            // reduce across the aligned 4-lane group
            p0 += __shfl_xor(p0, 1);  p1 += __shfl_xor(p1, 1);
            p0 += __shfl_xor(p0, 2);  p1 += __shfl_xor(p1, 2);
            if (k == q) { m0 = p0; m1 = p1; }   // in-group capture, no shuffle
        }
        float h0 = fmaxf(m0 + b0, 0.f);
        float h1 = fmaxf(m1 + b1, 0.f);
#pragma unroll
        for (int i = 0; i < LAYERS; ++i) {
            float t0 = fmaf(h0, layer_w[i*4+0], fmaf(h1, layer_w[i*4+1], layer_b[i*2+0]));
            float t1 = fmaf(h0, layer_w[i*4+2], fmaf(h1, layer_w[i*4+3], layer_b[i*2+1]));
            t0 = tanhf(t0);
            t1 = tanhf(t1);
            h0 = fmaf(t0, scale[i*2+0], shift[i*2+0]);
            h1 = fmaf(t1, scale[i*2+1], shift[i*2+1]);
        }
        const int orow = rbase + myrow;
        if (orow < Brows)
            out[orow] = fmaf(h0, fw0, fmaf(h1, fw1, fb));
    }
}

extern "C" void kernel_launch(void* const* d_in, const int* in_sizes, int n_in,
                              void* d_out, int out_size, void* d_ws, size_t ws_size,
                              hipStream_t stream) {
    const float* x       = (const float*)d_in[0];
    const float* pre_w   = (const float*)d_in[1];
    const float* pre_b   = (const float*)d_in[2];
    const float* layer_w = (const float*)d_in[3];
    const float* layer_b = (const float*)d_in[4];
    const float* scale   = (const float*)d_in[5];
    const float* shift   = (const float*)d_in[6];
    const float* final_w = (const float*)d_in[7];
    const float* final_b = (const float*)d_in[8];
    const float* head_w  = (const float*)d_in[9];
    const float* head_b  = (const float*)d_in[10];
    float* out = (float*)d_out;

    const int Brows = in_sizes[0] / 64;   // x is [B][64]
    const int threads = 256;              // 4 waves/block
    const int ntiles = (Brows + 63) >> 6;
    int blocks = 2048;                    // grid-stride; ~2 tiles/wave at B=2^20
    const int maxblocks = (ntiles + 3) / 4;
    if (blocks > maxblocks) blocks = maxblocks;
    if (blocks < 1) blocks = 1;

    fraud_fused_kernel<<<blocks, threads, 0, stream>>>(
        x, pre_w, pre_b, layer_w, layer_b, scale, shift,
        final_w, final_b, head_w, head_b, out, Brows);
}